// Round 1
// baseline (301.193 us; speedup 1.0000x reference)
//
#include <hip/hip_runtime.h>
#include <math.h>

#define ALPHA   0.99f
#define ONE_M   0.01f     // 1 - ALPHA
#define EPSV    1e-12f
#define T_LEN   4000
#define F_DIM   64
#define NCHUNK  16
#define CHUNK_L 250       // T_LEN / NCHUNK

// One block per batch row b. 1024 threads = 16 chunks x 64 features.
// Exact chunked scan:
//   mu_L  = a^L mu_0 + m_L
//   var_L = a^L var_0 + P + Q*mu_0 + R*mu_0^2
// with m,P,Q accumulated serially per chunk and R = a^(L+1) (1 - a^L).
__global__ __launch_bounds__(1024, 1)
void erbnorm_kernel(const float* __restrict__ x, float* __restrict__ out, float aL) {
    const int b   = blockIdx.x;
    const int tid = threadIdx.x;
    const int f   = tid & (F_DIM - 1);
    const int c   = tid >> 6;             // chunk index 0..15

    __shared__ float s_mL [NCHUNK][F_DIM];
    __shared__ float s_P  [NCHUNK][F_DIM];
    __shared__ float s_Q  [NCHUNK][F_DIM];
    __shared__ float s_mu [NCHUNK][F_DIM];   // entering mu per chunk
    __shared__ float s_var[NCHUNK][F_DIM];   // entering var per chunk

    const size_t base = ((size_t)b * T_LEN + (size_t)c * CHUNK_L) * F_DIM + f;
    const float* xp = x + base;

    // ---- pass 1: per-chunk transition coefficients ----
    {
        float m = 0.f, sp = 0.f, sq = 0.f, p = 1.f;
#pragma unroll 5
        for (int i = 0; i < CHUNK_L; ++i) {
            float xi = xp[(size_t)i * F_DIM];
            m = ALPHA * m + ONE_M * xi;      // m_i
            float u = xi - m;                // u_i = x_i - m_i
            p *= ALPHA;                      // p_i = a^i
            sp = ALPHA * sp + ONE_M * (u * u);
            sq = ALPHA * sq + ONE_M * (u * p);
        }
        s_mL[c][f] = m;
        s_P [c][f] = sp;
        s_Q [c][f] = -2.f * sq;
    }
    __syncthreads();

    // ---- combine: serial over 16 chunks, one thread per feature ----
    if (tid < F_DIM) {
        const float step = (-90.f - (-60.f)) / (float)(F_DIM - 1);
        float mu  = -60.f + (float)tid * step;
        float var = 40.f * 40.f;
        const float R = ALPHA * aL * (1.f - aL);   // a^(L+1) (1 - a^L)
        for (int cc = 0; cc < NCHUNK; ++cc) {
            s_mu [cc][tid] = mu;
            s_var[cc][tid] = var;
            float mu_n  = aL * mu  + s_mL[cc][tid];
            float var_n = aL * var + s_P[cc][tid] + s_Q[cc][tid] * mu + R * mu * mu;
            mu  = mu_n;
            var = var_n;
        }
    }
    __syncthreads();

    // ---- pass 2: replay chunk with exact entering state, emit outputs ----
    {
        float mu  = s_mu [c][f];
        float var = s_var[c][f];
        float* op = out + base;
#pragma unroll 5
        for (int i = 0; i < CHUNK_L; ++i) {
            float xi = xp[(size_t)i * F_DIM];
            mu = ALPHA * mu + ONE_M * xi;
            float d = xi - mu;
            var = ALPHA * var + ONE_M * (d * d);
            op[(size_t)i * F_DIM] = d / (sqrtf(var) + EPSV);
        }
    }
}

extern "C" void kernel_launch(void* const* d_in, const int* in_sizes, int n_in,
                              void* d_out, int out_size, void* d_ws, size_t ws_size,
                              hipStream_t stream) {
    const float* x = (const float*)d_in[0];
    float* out = (float*)d_out;
    const int B = 256;
    const float aL = (float)pow(0.99, (double)CHUNK_L);  // a^L, host-side
    hipLaunchKernelGGL(erbnorm_kernel, dim3(B), dim3(NCHUNK * F_DIM), 0, stream,
                       x, out, aL);
}

// Round 2
// 157.212 us; speedup vs baseline: 1.9158x; 1.9158x over previous
//
#include <hip/hip_runtime.h>
#include <math.h>

#define ALPHA   0.99f
#define ONE_M   0.01f     // 1 - ALPHA
#define T_LEN   4000
#define F_DIM   64
#define NCHUNK  80
#define CHUNK_L 50        // T_LEN / NCHUNK
#define FH      32        // features per block (F split across 2 blocks)
#define NG      8         // float4 groups per block = FH/4
#define NTHREADS (NCHUNK * NG)   // 640
#define PF      5         // prefetch depth (float4 loads in flight per thread)

typedef float f32x4 __attribute__((ext_vector_type(4)));

// Exact chunked scan, per (b, f):
//   mu_L  = a^L mu_0 + m_L                     (m: EMA of x within chunk)
//   var_L = a^L var_0 + SP + c2*SU*mu_0 + R*mu_0^2
//   SP = EMA of u^2, SU = sum of u (u = x - m), c2 = -2(1-a)a^L, R = a^{L+1}(1-a^L)
__global__ __launch_bounds__(NTHREADS, 5)
void erbnorm_kernel(const float* __restrict__ x, float* __restrict__ out, float aL) {
    const int blk = blockIdx.x;
    const int b   = blk >> 1;
    const int f0  = (blk & 1) * FH;
    const int tid = threadIdx.x;
    const int c   = tid >> 3;          // chunk 0..79
    const int g   = tid & 7;           // float4 group 0..7

    __shared__ float s_m [NCHUNK][FH];   // m  -> entering mu (in-place after combine)
    __shared__ float s_sp[NCHUNK][FH];   // SP -> entering var
    __shared__ float s_su[NCHUNK][FH];   // SU

    const size_t base = ((size_t)b * T_LEN + (size_t)c * CHUNK_L) * F_DIM + f0 + g * 4;
    const float* xp = x + base;

    // ---- pass 1: per-chunk transition coefficients (4 features per thread) ----
    {
        f32x4 m = 0.f, sp = 0.f, su = 0.f;
        for (int ii = 0; ii < CHUNK_L; ii += PF) {
            f32x4 v[PF];
#pragma unroll
            for (int j = 0; j < PF; ++j)
                v[j] = *(const f32x4*)(xp + (size_t)(ii + j) * F_DIM);
#pragma unroll
            for (int j = 0; j < PF; ++j) {
                f32x4 xi = v[j];
                m = ALPHA * m + ONE_M * xi;
                f32x4 u = xi - m;
                sp = ALPHA * sp + ONE_M * (u * u);
                su = su + u;
            }
        }
        *(f32x4*)&s_m [c][g * 4] = m;
        *(f32x4*)&s_sp[c][g * 4] = sp;
        *(f32x4*)&s_su[c][g * 4] = su;
    }
    __syncthreads();

    // ---- combine: serial chain over 80 chunks, one thread per feature ----
    if (tid < FH) {
        const float step = -30.f / 63.f;
        const int   fg   = f0 + tid;
        float mu  = -60.f + (float)fg * step;
        float var = 1600.f;
        const float R  = ALPHA * aL * (1.f - aL);   // a^(L+1)(1-a^L)
        const float c2 = -2.f * ONE_M * aL;         // -2(1-a)a^L
        for (int cc = 0; cc < NCHUNK; ++cc) {
            float m  = s_m [cc][tid];
            float sp = s_sp[cc][tid];
            float su = s_su[cc][tid];
            s_m [cc][tid] = mu;                     // entering state for pass 2
            s_sp[cc][tid] = var;
            float mu_n = aL * mu + m;
            var = aL * var + sp + (c2 * su) * mu + R * mu * mu;
            mu = mu_n;
        }
    }
    __syncthreads();

    // ---- pass 2: replay with exact entering state, emit outputs ----
    {
        f32x4 mu  = *(const f32x4*)&s_m [c][g * 4];
        f32x4 var = *(const f32x4*)&s_sp[c][g * 4];
        float* op = out + base;
        for (int ii = 0; ii < CHUNK_L; ii += PF) {
            f32x4 v[PF];
#pragma unroll
            for (int j = 0; j < PF; ++j)
                v[j] = *(const f32x4*)(xp + (size_t)(ii + j) * F_DIM);
#pragma unroll
            for (int j = 0; j < PF; ++j) {
                f32x4 xi = v[j];
                mu = ALPHA * mu + ONE_M * xi;
                f32x4 d = xi - mu;
                var = ALPHA * var + ONE_M * (d * d);
                f32x4 o;
                o[0] = d[0] * __builtin_amdgcn_rsqf(var[0]);
                o[1] = d[1] * __builtin_amdgcn_rsqf(var[1]);
                o[2] = d[2] * __builtin_amdgcn_rsqf(var[2]);
                o[3] = d[3] * __builtin_amdgcn_rsqf(var[3]);
                *(f32x4*)(op + (size_t)(ii + j) * F_DIM) = o;
            }
        }
    }
}

extern "C" void kernel_launch(void* const* d_in, const int* in_sizes, int n_in,
                              void* d_out, int out_size, void* d_ws, size_t ws_size,
                              hipStream_t stream) {
    const float* x = (const float*)d_in[0];
    float* out = (float*)d_out;
    const float aL = (float)pow(0.99, (double)CHUNK_L);  // a^L
    hipLaunchKernelGGL(erbnorm_kernel, dim3(512), dim3(NTHREADS), 0, stream,
                       x, out, aL);
}